// Round 1
// baseline (401.729 us; speedup 1.0000x reference)
//
#include <hip/hip_runtime.h>
#include <stdint.h>

// Problem constants (fixed by the reference)
#define Bc 4
#define Sc 2048
#define Dc 768
#define Kc 8192
#define NSc 2
#define Mc (Bc*Sc)            // 8192 tokens
#define EMB_ELEMS ((size_t)Mc*NSc*Dc)   // 12,582,912 floats: emb output, then indices

typedef __attribute__((ext_vector_type(8))) __bf16 bf16x8;
typedef __attribute__((ext_vector_type(4))) float f32x4;
typedef __attribute__((ext_vector_type(4))) unsigned short u16x4;

__device__ __forceinline__ unsigned short f2bf(float f){
  unsigned int u = __float_as_uint(f);
  u += 0x7FFFu + ((u >> 16) & 1u);       // round-to-nearest-even
  return (unsigned short)(u >> 16);
}
__device__ __forceinline__ float bf2f(unsigned short h){
  return __uint_as_float(((unsigned int)h) << 16);
}

// ---------------- K0: convert x,w f32 -> bf16 (into ws) ----------------
__global__ __launch_bounds__(256) void k_convert(const float4* __restrict__ x,
                                                 const float4* __restrict__ w,
                                                 u16x4* __restrict__ xb,
                                                 u16x4* __restrict__ wb){
  int i = blockIdx.x * 256 + threadIdx.x;   // grid sized exactly: (M*D/4)/256
  float4 v = x[i];
  u16x4 o;
  o.x = f2bf(v.x); o.y = f2bf(v.y); o.z = f2bf(v.z); o.w = f2bf(v.w);
  xb[i] = o;
  v = w[i];
  o.x = f2bf(v.x); o.y = f2bf(v.y); o.z = f2bf(v.z); o.w = f2bf(v.w);
  wb[i] = o;
}

// ---------------- K1: bf16 MFMA GEMM: logits[m][k] = sum_d x[m][d]*w[k][d] ----
// Output stored as bf16 rows with row stride 32768 ushorts (inside the indices
// region of d_out: token row t lives at byte offset t*65536, overwritten later).
#define BM 128
#define BN 128
#define BK 32

__global__ __launch_bounds__(256) void k_gemm(const unsigned short* __restrict__ xb,
                                              const unsigned short* __restrict__ wb,
                                              unsigned short* __restrict__ logits){
  __shared__ unsigned short As[BM*BK];   // 8 KB, linear (global_load_lds dest)
  __shared__ unsigned short Bs[BN*BK];   // 8 KB

  const int tid  = threadIdx.x;
  const int lane = tid & 63;
  const int wid  = tid >> 6;             // 4 waves, 2x2 -> each owns 64x64 out
  const int wm   = wid >> 1;
  const int wn   = wid & 1;
  const int bm0  = blockIdx.y * BM;
  const int bn0  = blockIdx.x * BN;

  f32x4 acc[4][4] = {};

  // staging: thread covers one 16B chunk per half-tile (64 rows per half)
  const int srow  = tid >> 2;            // 0..63
  const int scole = (tid & 3) * 8;       // element offset (8 bf16 = 16 B)
  const unsigned short* aS0 = xb + (size_t)(bm0 + srow) * Dc + scole;
  const unsigned short* aS1 = xb + (size_t)(bm0 + 64 + srow) * Dc + scole;
  const unsigned short* bS0 = wb + (size_t)(bn0 + srow) * Dc + scole;
  const unsigned short* bS1 = wb + (size_t)(bn0 + 64 + srow) * Dc + scole;
  // wave-uniform LDS dest bases (HW adds lane*16 bytes)
  unsigned short* aD0 = &As[wid * 512];
  unsigned short* aD1 = &As[2048 + wid * 512];
  unsigned short* bD0 = &Bs[wid * 512];
  unsigned short* bD1 = &Bs[2048 + wid * 512];

  const int fr = lane & 15;              // fragment row (A) / col (B)
  const int fk = (lane >> 4) * 8;        // k-run start

  for (int kt = 0; kt < Dc; kt += BK) {
    __syncthreads();                     // previous compute done before overwrite
    __builtin_amdgcn_global_load_lds((const __attribute__((address_space(1))) void*)(aS0 + kt),
                                     (__attribute__((address_space(3))) void*)aD0, 16, 0, 0);
    __builtin_amdgcn_global_load_lds((const __attribute__((address_space(1))) void*)(aS1 + kt),
                                     (__attribute__((address_space(3))) void*)aD1, 16, 0, 0);
    __builtin_amdgcn_global_load_lds((const __attribute__((address_space(1))) void*)(bS0 + kt),
                                     (__attribute__((address_space(3))) void*)bD0, 16, 0, 0);
    __builtin_amdgcn_global_load_lds((const __attribute__((address_space(1))) void*)(bS1 + kt),
                                     (__attribute__((address_space(3))) void*)bD1, 16, 0, 0);
    __syncthreads();                     // drains vmcnt before barrier

    bf16x8 a[4], b[4];
    #pragma unroll
    for (int i = 0; i < 4; i++) {
      a[i] = *(const bf16x8*)&As[(wm*64 + i*16 + fr) * BK + fk];
      b[i] = *(const bf16x8*)&Bs[(wn*64 + i*16 + fr) * BK + fk];
    }
    #pragma unroll
    for (int i = 0; i < 4; i++)
      #pragma unroll
      for (int j = 0; j < 4; j++)
        acc[i][j] = __builtin_amdgcn_mfma_f32_16x16x32_bf16(a[i], b[j], acc[i][j], 0, 0, 0);
  }

  // C/D layout: col = lane&15, row = (lane>>4)*4 + reg
  const int crow0 = bm0 + wm*64 + (lane >> 4) * 4;
  const int ccol0 = bn0 + wn*64 + (lane & 15);
  #pragma unroll
  for (int i = 0; i < 4; i++)
    #pragma unroll
    for (int j = 0; j < 4; j++)
      #pragma unroll
      for (int r = 0; r < 4; r++)
        logits[(size_t)(crow0 + i*16 + r) * 32768 + (ccol0 + j*16)] = f2bf(acc[i][j][r]);
}

// ---------------- K2: per-token argmax (approx + exact refine) + outputs ------
#define MARGIN 0.125f

__global__ __launch_bounds__(256) void k_select(const unsigned short* logits,   // bf16, row stride 32768 (aliases out_ind!)
                                                const float* __restrict__ gumbel,
                                                const float* __restrict__ x,
                                                const float* __restrict__ w,
                                                const float* __restrict__ emb_tab,
                                                float* __restrict__ out_emb,
                                                float* out_ind){
  const int t   = blockIdx.x;
  const int tid = threadIdx.x;
  const int lane = tid & 63, wid = tid >> 6;

  __shared__ unsigned short Lrow[Kc];    // 16 KB bf16 logits row
  __shared__ float wmax[4];
  __shared__ int   cand_k[16];
  __shared__ float cand_g[16];
  __shared__ int   cand_cnt;
  __shared__ int   sel_idx;

  // stage logits row t into LDS (before this block overwrites that memory)
  {
    const u16x4* src = (const u16x4*)(logits + (size_t)t * 32768);
    u16x4* dst = (u16x4*)Lrow;
    #pragma unroll
    for (int j = 0; j < 8; j++) dst[j*256 + tid] = src[j*256 + tid];
  }
  __syncthreads();

  for (int s = 0; s < NSc; ++s) {
    const float* grow = gumbel + ((size_t)t * NSc + s) * Kc;
    float4 vals[8];
    float m = -1e30f;
    #pragma unroll
    for (int j = 0; j < 8; j++) {
      float4 g4 = ((const float4*)grow)[j*256 + tid];
      u16x4 l4 = *(const u16x4*)&Lrow[j*1024 + tid*4];
      float4 v;
      v.x = bf2f(l4.x) + g4.x;
      v.y = bf2f(l4.y) + g4.y;
      v.z = bf2f(l4.z) + g4.z;
      v.w = bf2f(l4.w) + g4.w;
      vals[j] = v;
      m = fmaxf(m, fmaxf(fmaxf(v.x, v.y), fmaxf(v.z, v.w)));
    }
    #pragma unroll
    for (int off = 32; off; off >>= 1) m = fmaxf(m, __shfl_xor(m, off));
    if (lane == 0) wmax[wid] = m;
    __syncthreads();
    const float gmax = fmaxf(fmaxf(wmax[0], wmax[1]), fmaxf(wmax[2], wmax[3]));
    if (tid == 0) cand_cnt = 0;
    __syncthreads();

    const float thr = gmax - MARGIN;
    #pragma unroll
    for (int j = 0; j < 8; j++) {
      const int k0 = j*1024 + tid*4;
      float vv[4] = {vals[j].x, vals[j].y, vals[j].z, vals[j].w};
      #pragma unroll
      for (int q = 0; q < 4; q++) {
        if (vv[q] >= thr) {
          int p = atomicAdd(&cand_cnt, 1);
          if (p < 16) cand_k[p] = k0 + q;
        }
      }
    }
    __syncthreads();

    const int cnt = min(cand_cnt, 16);
    int idx;
    if (cnt == 1) {
      idx = cand_k[0];
    } else {
      // exact refine: wave `wid` takes candidates wid, wid+4, ...
      for (int c = wid; c < cnt; c += 4) {
        const int kc = cand_k[c];
        const float* wr = w + (size_t)kc * Dc;
        const float* xr = x + (size_t)t * Dc;
        double accd = 0.0;
        for (int d = lane; d < Dc; d += 64) accd += (double)xr[d] * (double)wr[d];
        #pragma unroll
        for (int off = 32; off; off >>= 1) accd += __shfl_xor(accd, off);
        if (lane == 0) cand_g[c] = (float)accd + grow[kc];  // f32 add, like ref
      }
      __syncthreads();
      if (tid == 0) {
        float bg = -1e30f; int bk_ = Kc;
        for (int c = 0; c < cnt; c++) {
          float g = cand_g[c]; int kk = cand_k[c];
          if (g > bg || (g == bg && kk < bk_)) { bg = g; bk_ = kk; }
        }
        sel_idx = bk_;
      }
      __syncthreads();
      idx = sel_idx;
    }

    // write one-hot indices row (overwrites the staged logits region for s=0)
    float* irow = out_ind + ((size_t)t * NSc + s) * Kc;
    #pragma unroll
    for (int j = 0; j < 8; j++) {
      const int k0 = j*1024 + tid*4;
      float4 z = {0.f, 0.f, 0.f, 0.f};
      const int d = idx - k0;
      if (d == 0) z.x = 1.0f; else if (d == 1) z.y = 1.0f;
      else if (d == 2) z.z = 1.0f; else if (d == 3) z.w = 1.0f;
      ((float4*)irow)[j*256 + tid] = z;
    }
    // gather embedding row
    const float* er = emb_tab + (size_t)idx * Dc;
    float* eo = out_emb + ((size_t)t * NSc + s) * Dc;
    for (int d = tid; d < Dc; d += 256) eo[d] = er[d];
    __syncthreads();   // protect shared reuse for next sample
  }
}

extern "C" void kernel_launch(void* const* d_in, const int* in_sizes, int n_in,
                              void* d_out, int out_size, void* d_ws, size_t ws_size,
                              hipStream_t stream) {
  const float* x   = (const float*)d_in[0];
  const float* w   = (const float*)d_in[1];
  const float* emb = (const float*)d_in[2];
  const float* gum = (const float*)d_in[3];
  // d_in[4] = num_samples (==2), compile-time constant here

  float* out_emb = (float*)d_out;
  float* out_ind = out_emb + EMB_ELEMS;
  // bf16 logits staged inside the indices region: token row t at ushort offset t*32768
  unsigned short* logits = (unsigned short*)out_ind;

  unsigned short* xb = (unsigned short*)d_ws;           // [M][D] bf16 (12.6 MB)
  unsigned short* wb = xb + (size_t)Mc * Dc;            // [K][D] bf16 (12.6 MB)

  const int n4 = (Mc * Dc) / 4;                         // per-array float4 count
  k_convert<<<n4 / 256, 256, 0, stream>>>((const float4*)x, (const float4*)w,
                                          (u16x4*)xb, (u16x4*)wb);
  dim3 gg(Kc / BN, Mc / BM);
  k_gemm<<<gg, 256, 0, stream>>>(xb, wb, logits);
  k_select<<<Mc, 256, 0, stream>>>(logits, gum, x, w, emb, out_emb, out_ind);
}